// Round 11
// baseline (217.502 us; speedup 1.0000x reference)
//
#include <hip/hip_runtime.h>
#include <math.h>

#define EPSF 1e-5f

typedef __attribute__((ext_vector_type(4))) float f32x4;
typedef __attribute__((ext_vector_type(4))) int i32x4;
typedef __attribute__((ext_vector_type(8))) int i32x8;

__device__ __forceinline__ unsigned short f2bf(float f) {
  unsigned int u = __float_as_uint(f);
  u += 0x7FFFu + ((u >> 16) & 1u);
  return (unsigned short)(u >> 16);
}
__device__ __forceinline__ float bf2f(unsigned short u) {
  return __uint_as_float((unsigned int)u << 16);
}

__device__ __forceinline__ void async_load16(const void* g, void* l) {
  __builtin_amdgcn_global_load_lds(
      (const __attribute__((address_space(1))) void*)g,
      (__attribute__((address_space(3))) void*)l, 16, 0, 0);
}

// MX fp8 layout: superblock = 16 rows x 128 k = 2048 B.
//   (row,k) -> sb = (row>>4)*NK + (k>>7)        (NK = K/128)
//   within:  l = ((k>>5)&3)*16 + (row&15); half = (k>>4)&1
//            byte = sb*2048 + half*1024 + l*16 + (k&15)

// ---- pack helper: 64x64 tile of W (rows=k, cols=n) -> MX fp8 pack ----
__device__ __forceinline__ void pack_tile(
    const float* __restrict__ Wsrc, unsigned char* __restrict__ Wdst,
    int WC, int NKW, int bid, int tid, float* smem) {
  int ncg = WC >> 6;
  int c0 = (bid % ncg) * 64, r0 = (bid / ncg) * 64;
  #pragma unroll
  for (int q = 0; q < 4; ++q) {
    int lin = q * 256 + tid;
    int r = lin >> 4, cq = lin & 15;
    float4 v = *(const float4*)(Wsrc + (size_t)(r0 + r) * WC + c0 + cq * 4);
    smem[r * 65 + cq * 4 + 0] = v.x; smem[r * 65 + cq * 4 + 1] = v.y;
    smem[r * 65 + cq * 4 + 2] = v.z; smem[r * 65 + cq * 4 + 3] = v.w;
  }
  __syncthreads();
  int c = tid & 63, kg = tid >> 6;
  int n = c0 + c;
  int k0 = r0 + kg * 16;
  int pk[4];
  #pragma unroll
  for (int q = 0; q < 4; ++q) {
    int p = __builtin_amdgcn_cvt_pk_fp8_f32(
        smem[(kg * 16 + q * 4 + 0) * 65 + c] * 16.0f,
        smem[(kg * 16 + q * 4 + 1) * 65 + c] * 16.0f, 0, false);
    pk[q] = __builtin_amdgcn_cvt_pk_fp8_f32(
        smem[(kg * 16 + q * 4 + 2) * 65 + c] * 16.0f,
        smem[(kg * 16 + q * 4 + 3) * 65 + c] * 16.0f, p, true);
  }
  size_t sb = (size_t)(n >> 4) * NKW + (k0 >> 7);
  int l = ((k0 >> 5) & 3) * 16 + (n & 15);
  int4 o4; o4.x = pk[0]; o4.y = pk[1]; o4.z = pk[2]; o4.w = pk[3];
  *(int4*)(Wdst + sb * 2048 + ((k0 >> 4) & 1) * 1024 + l * 16) = o4;
}

// ---- LN1 + dt: one token per block ----
__global__ __launch_bounds__(256) void k_ln1(
    const float* __restrict__ x, const float* __restrict__ g, const float* __restrict__ bta,
    const float* __restrict__ w_dt, const float* __restrict__ b_dt,
    const float* __restrict__ log_A, unsigned short* __restrict__ xn,
    float* __restrict__ log_a) {
  __shared__ float red[8];
  int bs = blockIdx.x;
  int t = threadIdx.x;
  float4 v = ((const float4*)(x + (size_t)bs * 1024))[t];
  float s = v.x + v.y + v.z + v.w;
  float ss = v.x * v.x + v.y * v.y + v.z * v.z + v.w * v.w;
  #pragma unroll
  for (int o = 1; o < 64; o <<= 1) { s += __shfl_xor(s, o); ss += __shfl_xor(ss, o); }
  int w = t >> 6;
  if ((t & 63) == 0) { red[w] = s; red[4 + w] = ss; }
  __syncthreads();
  float S = red[0] + red[1] + red[2] + red[3];
  float SS = red[4] + red[5] + red[6] + red[7];
  float m = S * (1.0f / 1024.0f);
  float var = SS * (1.0f / 1024.0f) - m * m;
  float inv = rsqrtf(var + EPSF);
  float4 gv = ((const float4*)g)[t];
  float4 bv = ((const float4*)bta)[t];
  float4 o;
  o.x = (v.x - m) * inv * gv.x + bv.x;
  o.y = (v.y - m) * inv * gv.y + bv.y;
  o.z = (v.z - m) * inv * gv.z + bv.z;
  o.w = (v.w - m) * inv * gv.w + bv.w;
  ushort4 ob;
  ob.x = f2bf(o.x); ob.y = f2bf(o.y); ob.z = f2bf(o.z); ob.w = f2bf(o.w);
  ((ushort4*)(xn + (size_t)bs * 1024))[t] = ob;
  float4 wv = ((const float4*)w_dt)[t & 7];
  float part = o.x * wv.x + o.y * wv.y + o.z * wv.z + o.w * wv.w;
  part += __shfl_xor(part, 1);
  part += __shfl_xor(part, 2);
  part += __shfl_xor(part, 4);
  if ((t & 7) == 0) {
    int r = t >> 3;
    float z = part + b_dt[0];
    float sp = (z > 20.0f) ? z : log1pf(expf(z));
    log_a[(size_t)bs * 32 + r] = sp * (-expf(log_A[r]));
  }
}

// ---- fused scan (blocks 0..511, single pass + decoupled lookback) +
// W1 pack (512..1535) + W2 pack (1536..2559).
// Lookback sync: release STORE publish + relaxed agent-scope LOAD poll with
// s_sleep backoff (r10's atomicAdd-RMW polling convoyed the fabric: 56us @ 3%
// VALU). Loads don't serialize at the coherence point; sleep cuts poll rate.
__global__ __launch_bounds__(256) void k_scanf(
    const unsigned short* __restrict__ xn, const float* __restrict__ x,
    const float* __restrict__ loga, float4* __restrict__ E, float* __restrict__ P,
    const float* __restrict__ bb2, float* __restrict__ out,
    const float* __restrict__ W1, unsigned char* __restrict__ W1t,
    const float* __restrict__ W2, unsigned char* __restrict__ W2t,
    int* __restrict__ flags) {
  __shared__ __align__(16) float smem[64 * 65];
  int tid = threadIdx.x;
  int bx = blockIdx.x;
  if (bx >= 512) {
    int bid = bx - 512;
    if (bid < 1024) pack_tile(W1, W1t, 4096, 8, bid, tid, smem);
    else            pack_tile(W2, W2t, 1024, 32, bid - 1024, tid, smem);
    return;
  }
  float* dec = smem;                         // [128]
  float4* sE = (float4*)(smem + 128);        // [32][8]
  float* sP = smem + 128 + 1024;             // [32]
  int b = bx >> 8, r = (bx >> 3) & 31, ch = bx & 7;
  int cg = tid & 7, sub = tid >> 3;
  if (tid < 128)
    dec[tid] = expf(loga[(size_t)(b * 1024 + ch * 128 + tid) * 32 + r]);
  __syncthreads();
  int t0 = ch * 128 + sub * 4;
  size_t base = ((size_t)(b * 1024 + t0) * 1024 + r * 32 + cg * 4) >> 2;
  const ushort4* xn4 = (const ushort4*)xn;
  float4 xv[4];
  #pragma unroll
  for (int i = 0; i < 4; ++i) {
    ushort4 u = xn4[base + (size_t)i * 256];
    xv[i].x = bf2f(u.x); xv[i].y = bf2f(u.y); xv[i].z = bf2f(u.z); xv[i].w = bf2f(u.w);
  }
  float4 S = {0.f, 0.f, 0.f, 0.f};
  float Pl = 1.0f;
  #pragma unroll
  for (int i = 0; i < 4; ++i) {
    float d = dec[sub * 4 + i];
    S.x = d * S.x + xv[i].x; S.y = d * S.y + xv[i].y;
    S.z = d * S.z + xv[i].z; S.w = d * S.w + xv[i].w;
    Pl *= d;
  }
  sE[sub * 8 + cg] = S;
  if (cg == 0) sP[sub] = Pl;
  __syncthreads();
  // publish chunk aggregate (E8, P) with release fence
  if (tid < 8) {
    float4 Et = {0.f, 0.f, 0.f, 0.f};
    float PP = 1.0f;
    #pragma unroll
    for (int h = 0; h < 32; ++h) {
      float p = sP[h]; float4 e = sE[h * 8 + tid];
      Et.x = p * Et.x + e.x; Et.y = p * Et.y + e.y;
      Et.z = p * Et.z + e.z; Et.w = p * Et.w + e.w;
      PP *= p;
    }
    E[((size_t)(b * 32 + r) * 8 + ch) * 8 + tid] = Et;
    if (tid == 0) P[(b * 32 + r) * 8 + ch] = PP;
    __threadfence();
  }
  __syncthreads();
  int lkbase = (b * 32 + r) * 8;
  if (tid == 0) {
    __hip_atomic_store(&flags[lkbase + ch], 1, __ATOMIC_RELEASE,
                       __HIP_MEMORY_SCOPE_AGENT);
    for (int h = 0; h < ch; ++h)
      while (__hip_atomic_load(&flags[lkbase + h], __ATOMIC_ACQUIRE,
                               __HIP_MEMORY_SCOPE_AGENT) == 0)
        __builtin_amdgcn_s_sleep(8);
    __threadfence();
  }
  __syncthreads();
  // finalize: global prefix (h<ch) + local prefix (h<sub) + write out
  {
    float4 Sin = {0.f, 0.f, 0.f, 0.f};
    const float4* Eb = E + (size_t)(b * 32 + r) * 64 + cg;
    const float* Pb = P + (size_t)(b * 32 + r) * 8;
    for (int h = 0; h < ch; ++h) {
      float p = Pb[h]; float4 e = Eb[h * 8];
      Sin.x = p * Sin.x + e.x; Sin.y = p * Sin.y + e.y;
      Sin.z = p * Sin.z + e.z; Sin.w = p * Sin.w + e.w;
    }
    for (int h = 0; h < sub; ++h) {
      float p = sP[h]; float4 e = sE[h * 8 + cg];
      Sin.x = p * Sin.x + e.x; Sin.y = p * Sin.y + e.y;
      Sin.z = p * Sin.z + e.z; Sin.w = p * Sin.w + e.w;
    }
    float4 bb = ((const float4*)bb2)[r * 8 + cg];
    const float4* x4 = (const float4*)x;
    float4* out4 = (float4*)out;
    #pragma unroll
    for (int i = 0; i < 4; ++i) {
      float d = dec[sub * 4 + i];
      Sin.x = d * Sin.x + xv[i].x; Sin.y = d * Sin.y + xv[i].y;
      Sin.z = d * Sin.z + xv[i].z; Sin.w = d * Sin.w + xv[i].w;
      float4 rx = x4[base + (size_t)i * 256];
      float4 oi;
      oi.x = Sin.x + rx.x + bb.x; oi.y = Sin.y + rx.y + bb.y;
      oi.z = Sin.z + rx.z + bb.z; oi.w = Sin.w + rx.w + bb.w;
      out4[base + (size_t)i * 256] = oi;
    }
  }
}

// ---- LN2: 16 tokens/block; reads out, subtracts bb2 -> fn (fp8, MX pack NK=8).
__global__ __launch_bounds__(256) void k_ln2(
    const float* __restrict__ out, const float* __restrict__ bb2,
    const float* __restrict__ g, const float* __restrict__ bta,
    unsigned char* __restrict__ fn) {
  __shared__ __align__(16) unsigned char sC[16384];
  int tid = threadIdx.x;
  int t15 = tid >> 4;                 // token within block
  int kc = tid & 15;
  int tok = (blockIdx.x << 4) + t15;
  const float4* row = (const float4*)(out + (size_t)tok * 1024);
  const float4* b4 = (const float4*)bb2;
  float4 v[16];
  float s = 0.f, ss = 0.f;
  #pragma unroll
  for (int ci = 0; ci < 4; ++ci) {
    int cc = kc + ci * 16;
    #pragma unroll
    for (int q = 0; q < 4; ++q) {
      float4 xv = row[cc * 4 + q];
      float4 bb = b4[cc * 4 + q];
      xv.x -= bb.x; xv.y -= bb.y; xv.z -= bb.z; xv.w -= bb.w;
      v[ci * 4 + q] = xv;
      s += xv.x + xv.y + xv.z + xv.w;
      ss += xv.x * xv.x + xv.y * xv.y + xv.z * xv.z + xv.w * xv.w;
    }
  }
  #pragma unroll
  for (int o = 1; o < 16; o <<= 1) { s += __shfl_xor(s, o); ss += __shfl_xor(ss, o); }
  float m = s * (1.0f / 1024.0f);
  float var = ss * (1.0f / 1024.0f) - m * m;
  float inv = rsqrtf(var + EPSF);
  #pragma unroll
  for (int ci = 0; ci < 4; ++ci) {
    int cc = kc + ci * 16;
    int pk[4];
    #pragma unroll
    for (int q = 0; q < 4; ++q) {
      float4 gv = ((const float4*)g)[cc * 4 + q];
      float4 bv = ((const float4*)bta)[cc * 4 + q];
      float4 xv = v[ci * 4 + q];
      float f0 = (xv.x - m) * inv * gv.x + bv.x;
      float f1 = (xv.y - m) * inv * gv.y + bv.y;
      float f2 = (xv.z - m) * inv * gv.z + bv.z;
      float f3 = (xv.w - m) * inv * gv.w + bv.w;
      int p = __builtin_amdgcn_cvt_pk_fp8_f32(f0, f1, 0, false);
      pk[q] = __builtin_amdgcn_cvt_pk_fp8_f32(f2, f3, p, true);
    }
    int loc = (cc >> 3) * 2048 + (cc & 1) * 1024 + (((cc >> 1) & 3) * 16 + t15) * 16;
    loc ^= ((loc >> 8) & 7) << 4;     // bank swizzle (involution)
    int4 o4; o4.x = pk[0]; o4.y = pk[1]; o4.z = pk[2]; o4.w = pk[3];
    *(int4*)(sC + loc) = o4;
  }
  __syncthreads();
  unsigned char* dst = fn + (size_t)blockIdx.x * 16384;
  #pragma unroll
  for (int p = 0; p < 4; ++p) {
    int a = (p * 256 + tid) * 16;
    int sa = a ^ (((a >> 8) & 7) << 4);
    *(int4*)(dst + a) = *(const int4*)(sC + sa);
  }
}

// ---- GEMM1: 128x128 tile, K=1024, BK=128, 8 stages, double-buffered LDS with
// counted vmcnt prefetch. Epilogue: fast-gelu(acc/16+bias) -> fp8 -> LDS repack
// -> hbf (MX pack NK=32)   [round-5 measured best form]
__global__ __launch_bounds__(256, 2) void k_gemm1(
    const unsigned char* __restrict__ Ap, const unsigned char* __restrict__ Bp,
    const float* __restrict__ bias, unsigned char* __restrict__ C8) {
  __shared__ __align__(16) unsigned char sAB[65536];   // 2 x (16K A + 16K B)
  int L = blockIdx.x;
  int xcd = L & 7;
  int nq = xcd & 3, mh = xcd >> 2;
  int rest = L >> 3;
  int nx = rest & 7, my = rest >> 3;
  int n0 = (nq * 8 + nx) * 128;
  int m0 = (mh * 8 + my) * 128;
  int tid = threadIdx.x;
  int wave = tid >> 6, lane = tid & 63;
  int wr = wave >> 1, wc = wave & 1;
  int l15 = lane & 15, quad = lane >> 4;

  f32x4 zero = {0.0f, 0.0f, 0.0f, 0.0f};
  f32x4 acc[4][4];
  #pragma unroll
  for (int i = 0; i < 4; ++i)
    #pragma unroll
    for (int j = 0; j < 4; ++j) acc[i][j] = zero;

  const unsigned char* gsrc = (wave < 2) ? Ap : Bp;
  int rt0 = (wave < 2) ? (m0 >> 4) : (n0 >> 4);
  int aoff = (wave < 2) ? 0 : 16384;
  int w01 = wave & 1;

  #pragma unroll
  for (int t = 0; t < 8; ++t) {
    int idx = w01 * 8 + t, rt = idx >> 1, h = idx & 1;
    async_load16(gsrc + ((size_t)(rt0 + rt) * 8 + 0) * 2048 + h * 1024 + lane * 16,
                 sAB + aoff + rt * 2048 + h * 1024 + lane * 16);
  }

  #pragma unroll 1
  for (int st = 0; st < 8; ++st) {
    int cur = (st & 1) * 32768;
    if (st < 7) {
      int nxt = cur ^ 32768;
      #pragma unroll
      for (int t = 0; t < 8; ++t) {
        int idx = w01 * 8 + t, rt = idx >> 1, h = idx & 1;
        async_load16(gsrc + ((size_t)(rt0 + rt) * 8 + st + 1) * 2048 + h * 1024 + lane * 16,
                     sAB + nxt + aoff + rt * 2048 + h * 1024 + lane * 16);
      }
      asm volatile("s_waitcnt vmcnt(8)" ::: "memory");
    } else {
      asm volatile("s_waitcnt vmcnt(0)" ::: "memory");
    }
    __builtin_amdgcn_s_barrier();
    const unsigned char* sA = sAB + cur;
    const unsigned char* sB = sAB + cur + 16384;
    // cache B fragments; stream A fragments (round-5 form)
    i32x8 bf[4];
    #pragma unroll
    for (int j = 0; j < 4; ++j) {
      const unsigned char* pb = sB + (wc * 4 + j) * 2048 + lane * 16;
      i32x4 lo = *(const i32x4*)pb;
      i32x4 hi = *(const i32x4*)(pb + 1024);
      bf[j] = __builtin_shufflevector(lo, hi, 0, 1, 2, 3, 4, 5, 6, 7);
    }
    #pragma unroll
    for (int i = 0; i < 4; ++i) {
      const unsigned char* pa = sA + (wr * 4 + i) * 2048 + lane * 16;
      i32x4 lo = *(const i32x4*)pa;
      i32x4 hi = *(const i32x4*)(pa + 1024);
      i32x8 a = __builtin_shufflevector(lo, hi, 0, 1, 2, 3, 4, 5, 6, 7);
      #pragma unroll
      for (int j = 0; j < 4; ++j)
        acc[i][j] = __builtin_amdgcn_mfma_scale_f32_16x16x128_f8f6f4(
            a, bf[j], acc[i][j], 0, 0, 0, 0x7F7F7F7F, 0, 0x7F7F7F7F);
    }
    asm volatile("s_waitcnt lgkmcnt(0)" ::: "memory");
    __builtin_amdgcn_s_barrier();
  }

  // epilogue: fast gelu (sigmoid-form tanh approx; err ~3e-3 << fp8 step)
  unsigned char* sC = sAB;
  #pragma unroll
  for (int i = 0; i < 4; ++i) {
    #pragma unroll
    for (int j = 0; j < 4; ++j) {
      int col_l = wc * 64 + j * 16 + l15;    // k_l of GEMM2, 0..127
      float bval = bias[n0 + col_l];
      int half2 = (col_l >> 4) & 1, lb = (col_l >> 5) & 3;
      unsigned char* ld = sC + (wr * 4 + i) * 2048 + half2 * 1024 +
                          (lb * 16 + quad * 4) * 16 + l15;
      float vv[4];
      #pragma unroll
      for (int v = 0; v < 4; ++v) {
        float val = acc[i][j][v] * 0.0625f + bval;
        float u = val * (0.7978845608f + 0.035677408f * val * val);
        vv[v] = val / (1.0f + __expf(-2.0f * u));
      }
      int p01 = __builtin_amdgcn_cvt_pk_fp8_f32(vv[0], vv[1], 0, false);
      int p23 = __builtin_amdgcn_cvt_pk_fp8_f32(vv[2], vv[3], 0, false);
      ld[0 * 16] = (unsigned char)(p01 & 0xff);
      ld[1 * 16] = (unsigned char)((p01 >> 8) & 0xff);
      ld[2 * 16] = (unsigned char)(p23 & 0xff);
      ld[3 * 16] = (unsigned char)((p23 >> 8) & 0xff);
    }
  }
  __syncthreads();
  int mt2_0 = m0 >> 4, kp2 = n0 >> 7;       // hbf: NK2 = 32
  #pragma unroll
  for (int p = 0; p < 4; ++p) {
    int ci = p * 256 + tid;
    int s = ci >> 7, off = (ci & 127) * 16;
    *(int4*)(C8 + ((size_t)(mt2_0 + s) * 32 + kp2) * 2048 + off) =
        *(const int4*)(sC + s * 2048 + off);
  }
}

// ---- GEMM2: 64x64 tile, full K=4096 (no split-K, no atomics), BK=256,
// 16 stages, 512 blocks (2/CU), double-buffered LDS, counted vmcnt prefetch.
// 2D XCD swizzle: xcd = (m-quarter<<1)|n-half -> 2MB A + 2MB B per XCD (L2-fit).
// Epilogue: plain RMW out += acc/16.   [round-5 measured winner]
__global__ __launch_bounds__(256, 2) void k_gemm2(
    const unsigned char* __restrict__ Ap, const unsigned char* __restrict__ Bp,
    float* __restrict__ O) {
  __shared__ __align__(16) unsigned char sAB[65536];   // 2 x (16K A + 16K B)
  int L = blockIdx.x;
  int xcd = L & 7;
  int mq = xcd >> 1, nh = xcd & 1;
  int rest = L >> 3;
  int nx = rest & 7, my = rest >> 3;
  int n0 = (nh * 8 + nx) * 64;
  int m0 = (mq * 8 + my) * 64;
  int tid = threadIdx.x;
  int wave = tid >> 6, lane = tid & 63;
  int wr = wave >> 1, wc = wave & 1;
  int l15 = lane & 15, quad = lane >> 4;

  f32x4 zero = {0.0f, 0.0f, 0.0f, 0.0f};
  f32x4 acc[2][2];
  #pragma unroll
  for (int i = 0; i < 2; ++i)
    #pragma unroll
    for (int j = 0; j < 2; ++j) acc[i][j] = zero;

  const unsigned char* gsrc = (wave < 2) ? Ap : Bp;
  int rt0 = (wave < 2) ? (m0 >> 4) : (n0 >> 4);
  int aoff = (wave < 2) ? 0 : 16384;
  int w01 = wave & 1;

  #pragma unroll
  for (int t = 0; t < 8; ++t) {
    int idx = w01 * 8 + t, sb = idx >> 1, h = idx & 1;
    int rt = sb >> 1, kt = sb & 1;
    async_load16(gsrc + ((size_t)(rt0 + rt) * 32 + kt) * 2048 + h * 1024 + lane * 16,
                 sAB + aoff + sb * 2048 + h * 1024 + lane * 16);
  }

  #pragma unroll 1
  for (int st = 0; st < 16; ++st) {
    int cur = (st & 1) * 32768;
    if (st < 15) {
      int nxt = cur ^ 32768;
      #pragma unroll
      for (int t = 0; t < 8; ++t) {
        int idx = w01 * 8 + t, sb = idx >> 1, h = idx & 1;
        int rt = sb >> 1, kt = sb & 1;
        async_load16(
            gsrc + ((size_t)(rt0 + rt) * 32 + (st + 1) * 2 + kt) * 2048 + h * 1024 + lane * 16,
            sAB + nxt + aoff + sb * 2048 + h * 1024 + lane * 16);
      }
      asm volatile("s_waitcnt vmcnt(8)" ::: "memory");
    } else {
      asm volatile("s_waitcnt vmcnt(0)" ::: "memory");
    }
    __builtin_amdgcn_s_barrier();
    const unsigned char* sA = sAB + cur;
    const unsigned char* sB = sAB + cur + 16384;
    #pragma unroll
    for (int kl = 0; kl < 2; ++kl) {
      i32x8 af[2], bf[2];
      #pragma unroll
      for (int i = 0; i < 2; ++i) {
        const unsigned char* pa = sA + ((wr * 2 + i) * 2 + kl) * 2048 + lane * 16;
        i32x4 lo = *(const i32x4*)pa;
        i32x4 hi = *(const i32x4*)(pa + 1024);
        af[i] = __builtin_shufflevector(lo, hi, 0, 1, 2, 3, 4, 5, 6, 7);
      }
      #pragma unroll
      for (int j = 0; j < 2; ++j) {
        const unsigned char* pb = sB + ((wc * 2 + j) * 2 + kl) * 2048 + lane * 16;
        i32x4 lo = *(const i32x4*)pb;
        i32x4 hi = *(const i32x4*)(pb + 1024);
        bf[j] = __builtin_shufflevector(lo, hi, 0, 1, 2, 3, 4, 5, 6, 7);
      }
      #pragma unroll
      for (int i = 0; i < 2; ++i)
        #pragma unroll
        for (int j = 0; j < 2; ++j)
          acc[i][j] = __builtin_amdgcn_mfma_scale_f32_16x16x128_f8f6f4(
              af[i], bf[j], acc[i][j], 0, 0, 0, 0x7F7F7F7F, 0, 0x7F7F7F7F);
    }
    asm volatile("s_waitcnt lgkmcnt(0)" ::: "memory");
    __builtin_amdgcn_s_barrier();
  }

  // epilogue: plain read-modify-write (unique block per output tile)
  #pragma unroll
  for (int i = 0; i < 2; ++i)
    #pragma unroll
    for (int j = 0; j < 2; ++j) {
      int col = n0 + wc * 32 + j * 16 + l15;
      #pragma unroll
      for (int v = 0; v < 4; ++v) {
        int row = m0 + wr * 32 + i * 16 + quad * 4 + v;
        float* p = &O[(size_t)row * 1024 + col];
        *p = *p + acc[i][j][v] * 0.0625f;
      }
    }
}

extern "C" void kernel_launch(void* const* d_in, const int* in_sizes, int n_in,
                              void* d_out, int out_size, void* d_ws, size_t ws_size,
                              hipStream_t stream) {
  const float* x     = (const float*)d_in[0];
  const float* log_A = (const float*)d_in[1];
  const float* w_dt  = (const float*)d_in[2];
  const float* b_dt  = (const float*)d_in[3];
  const float* g_ssm = (const float*)d_in[4];
  const float* b_ssm = (const float*)d_in[5];
  const float* g_ffn = (const float*)d_in[6];
  const float* b_ffn = (const float*)d_in[7];
  const float* W1    = (const float*)d_in[8];
  const float* bb1   = (const float*)d_in[9];
  const float* W2    = (const float*)d_in[10];
  const float* bb2   = (const float*)d_in[11];
  float* out = (float*)d_out;

  const size_t MB = 1u << 20;
  char* ws = (char*)d_ws;
  unsigned short* xn   = (unsigned short*)(ws);              // 0-4 bf16
  unsigned char* W1t   = (unsigned char*)(ws + 4 * MB);      // 4-8 fp8 MX-pack
  float* loga          = (float*)(ws + 8 * MB);              // 256 KB
  float4* Ebuf         = (float4*)(ws + 8 * MB + 262144);    // 64 KB
  float* Pbuf          = (float*)(ws + 8 * MB + 393216);     // 2 KB
  int* flags           = (int*)(ws + 8 * MB + 409600);       // 4 KB (zeroed)
  unsigned char* fn    = (unsigned char*)(ws + 9 * MB);      // 9-11 fp8 MX-pack
  unsigned char* W2t   = (unsigned char*)(ws + 11 * MB);     // 11-15 fp8 MX-pack
  unsigned char* hbf   = (unsigned char*)(ws + 15 * MB);     // 15-23 fp8 MX-pack

  hipMemsetAsync(flags, 0, 4096, stream);
  k_ln1<<<2048, 256, 0, stream>>>(x, g_ssm, b_ssm, w_dt, b_dt, log_A, xn, loga);
  // fused single-pass scan w/ decoupled lookback (512) + W1 pack (1024) + W2 pack (1024)
  k_scanf<<<2560, 256, 0, stream>>>(xn, x, loga, Ebuf, Pbuf, bb2, out,
                                    W1, W1t, W2, W2t, flags);
  k_ln2<<<128, 256, 0, stream>>>(out, bb2, g_ffn, b_ffn, fn);
  // GEMM1: M=2048, N=4096, K=1024 (NK=8), 512 blocks
  k_gemm1<<<512, 256, 0, stream>>>(fn, W1t, bb1, hbf);
  // GEMM2: M=2048, N=1024, K=4096 (NK=32), 512 blocks, full-K, no atomics
  k_gemm2<<<512, 256, 0, stream>>>(hbf, W2t, out);
}

// Round 12
// 148.717 us; speedup vs baseline: 1.4625x; 1.4625x over previous
//
#include <hip/hip_runtime.h>
#include <math.h>

#define EPSF 1e-5f

typedef __attribute__((ext_vector_type(4))) float f32x4;
typedef __attribute__((ext_vector_type(4))) int i32x4;
typedef __attribute__((ext_vector_type(8))) int i32x8;

__device__ __forceinline__ unsigned short f2bf(float f) {
  unsigned int u = __float_as_uint(f);
  u += 0x7FFFu + ((u >> 16) & 1u);
  return (unsigned short)(u >> 16);
}
__device__ __forceinline__ float bf2f(unsigned short u) {
  return __uint_as_float((unsigned int)u << 16);
}

__device__ __forceinline__ void async_load16(const void* g, void* l) {
  __builtin_amdgcn_global_load_lds(
      (const __attribute__((address_space(1))) void*)g,
      (__attribute__((address_space(3))) void*)l, 16, 0, 0);
}

// MX fp8 layout: superblock = 16 rows x 128 k = 2048 B.
//   (row,k) -> sb = (row>>4)*NK + (k>>7)        (NK = K/128)
//   within:  l = ((k>>5)&3)*16 + (row&15); half = (k>>4)&1
//            byte = sb*2048 + half*1024 + l*16 + (k&15)
// Each half (1024 B) is one wave-wide global_load_lds (base + lane*16); fragment
// reads are linear ds_read_b128 at lane*16 (+1024) -> conflict-free. With unit
// scales the HW k-ordering is identical for A and B -> dot invariant.

// ---- LN1 + dt: one token per block ----
__global__ __launch_bounds__(256) void k_ln1(
    const float* __restrict__ x, const float* __restrict__ g, const float* __restrict__ bta,
    const float* __restrict__ w_dt, const float* __restrict__ b_dt,
    const float* __restrict__ log_A, unsigned short* __restrict__ xn,
    float* __restrict__ log_a) {
  __shared__ float red[8];
  int bs = blockIdx.x;
  int t = threadIdx.x;
  float4 v = ((const float4*)(x + (size_t)bs * 1024))[t];
  float s = v.x + v.y + v.z + v.w;
  float ss = v.x * v.x + v.y * v.y + v.z * v.z + v.w * v.w;
  #pragma unroll
  for (int o = 1; o < 64; o <<= 1) { s += __shfl_xor(s, o); ss += __shfl_xor(ss, o); }
  int w = t >> 6;
  if ((t & 63) == 0) { red[w] = s; red[4 + w] = ss; }
  __syncthreads();
  float S = red[0] + red[1] + red[2] + red[3];
  float SS = red[4] + red[5] + red[6] + red[7];
  float m = S * (1.0f / 1024.0f);
  float var = SS * (1.0f / 1024.0f) - m * m;
  float inv = rsqrtf(var + EPSF);
  float4 gv = ((const float4*)g)[t];
  float4 bv = ((const float4*)bta)[t];
  float4 o;
  o.x = (v.x - m) * inv * gv.x + bv.x;
  o.y = (v.y - m) * inv * gv.y + bv.y;
  o.z = (v.z - m) * inv * gv.z + bv.z;
  o.w = (v.w - m) * inv * gv.w + bv.w;
  ushort4 ob;
  ob.x = f2bf(o.x); ob.y = f2bf(o.y); ob.z = f2bf(o.z); ob.w = f2bf(o.w);
  ((ushort4*)(xn + (size_t)bs * 1024))[t] = ob;
  float4 wv = ((const float4*)w_dt)[t & 7];
  float part = o.x * wv.x + o.y * wv.y + o.z * wv.z + o.w * wv.w;
  part += __shfl_xor(part, 1);
  part += __shfl_xor(part, 2);
  part += __shfl_xor(part, 4);
  if ((t & 7) == 0) {
    int r = t >> 3;
    float z = part + b_dt[0];
    float sp = (z > 20.0f) ? z : log1pf(expf(z));
    log_a[(size_t)bs * 32 + r] = sp * (-expf(log_A[r]));
  }
}

// ---- scan pass (blocks 0..511) + weight pack (blocks 512..1535), co-scheduled.
// PASS 0: scan partials + W1 pack (NK=8).  PASS 1: scan finalize + W2 pack (NK=32).
template <int PASS, int NKW>
__global__ __launch_bounds__(256) void k_scan_pack(
    const unsigned short* __restrict__ xn, const float* __restrict__ x,
    const float* __restrict__ loga, float4* __restrict__ E, float* __restrict__ P,
    const float* __restrict__ bb2, float* __restrict__ out,
    const float* __restrict__ Wsrc, unsigned char* __restrict__ Wdst, int WC) {
  __shared__ __align__(16) float smem[64 * 65];
  int tid = threadIdx.x;
  if (blockIdx.x >= 512) {
    // ---- weight pack: 64x64 tile of W (rows=k, cols=n) -> MX fp8 pack ----
    int bid = blockIdx.x - 512;
    int ncg = WC >> 6;                       // col-groups
    int c0 = (bid % ncg) * 64, r0 = (bid / ncg) * 64;
    #pragma unroll
    for (int q = 0; q < 4; ++q) {
      int lin = q * 256 + tid;
      int r = lin >> 4, cq = lin & 15;
      float4 v = *(const float4*)(Wsrc + (size_t)(r0 + r) * WC + c0 + cq * 4);
      smem[r * 65 + cq * 4 + 0] = v.x; smem[r * 65 + cq * 4 + 1] = v.y;
      smem[r * 65 + cq * 4 + 2] = v.z; smem[r * 65 + cq * 4 + 3] = v.w;
    }
    __syncthreads();
    int c = tid & 63, kg = tid >> 6;
    int n = c0 + c;
    int k0 = r0 + kg * 16;
    int pk[4];
    #pragma unroll
    for (int q = 0; q < 4; ++q) {
      int p = __builtin_amdgcn_cvt_pk_fp8_f32(
          smem[(kg * 16 + q * 4 + 0) * 65 + c] * 16.0f,
          smem[(kg * 16 + q * 4 + 1) * 65 + c] * 16.0f, 0, false);
      pk[q] = __builtin_amdgcn_cvt_pk_fp8_f32(
          smem[(kg * 16 + q * 4 + 2) * 65 + c] * 16.0f,
          smem[(kg * 16 + q * 4 + 3) * 65 + c] * 16.0f, p, true);
    }
    size_t sb = (size_t)(n >> 4) * NKW + (k0 >> 7);
    int l = ((k0 >> 5) & 3) * 16 + (n & 15);
    int4 o4; o4.x = pk[0]; o4.y = pk[1]; o4.z = pk[2]; o4.w = pk[3];
    *(int4*)(Wdst + sb * 2048 + ((k0 >> 4) & 1) * 1024 + l * 16) = o4;
    return;
  }
  // ---- scan ----
  float* dec = smem;                         // [128]
  float4* sE = (float4*)(smem + 128);        // [32][8]
  float* sP = smem + 128 + 1024;             // [32]
  int bx = blockIdx.x;
  int b = bx >> 8, r = (bx >> 3) & 31, ch = bx & 7;
  int cg = tid & 7, sub = tid >> 3;
  if (tid < 128)
    dec[tid] = expf(loga[(size_t)(b * 1024 + ch * 128 + tid) * 32 + r]);
  __syncthreads();
  int t0 = ch * 128 + sub * 4;
  size_t base = ((size_t)(b * 1024 + t0) * 1024 + r * 32 + cg * 4) >> 2;
  const ushort4* xn4 = (const ushort4*)xn;
  float4 xv[4];
  #pragma unroll
  for (int i = 0; i < 4; ++i) {
    ushort4 u = xn4[base + (size_t)i * 256];
    xv[i].x = bf2f(u.x); xv[i].y = bf2f(u.y); xv[i].z = bf2f(u.z); xv[i].w = bf2f(u.w);
  }
  float4 S = {0.f, 0.f, 0.f, 0.f};
  float Pl = 1.0f;
  #pragma unroll
  for (int i = 0; i < 4; ++i) {
    float d = dec[sub * 4 + i];
    S.x = d * S.x + xv[i].x; S.y = d * S.y + xv[i].y;
    S.z = d * S.z + xv[i].z; S.w = d * S.w + xv[i].w;
    Pl *= d;
  }
  sE[sub * 8 + cg] = S;
  if (cg == 0) sP[sub] = Pl;
  __syncthreads();
  if (PASS == 0) {
    if (tid < 8) {
      float4 Et = {0.f, 0.f, 0.f, 0.f};
      float PP = 1.0f;
      #pragma unroll
      for (int h = 0; h < 32; ++h) {
        float p = sP[h]; float4 e = sE[h * 8 + tid];
        Et.x = p * Et.x + e.x; Et.y = p * Et.y + e.y;
        Et.z = p * Et.z + e.z; Et.w = p * Et.w + e.w;
        PP *= p;
      }
      E[((size_t)(b * 32 + r) * 8 + ch) * 8 + tid] = Et;
      if (tid == 0) P[(b * 32 + r) * 8 + ch] = PP;
    }
  } else {
    float4 Sin = {0.f, 0.f, 0.f, 0.f};
    const float4* Eb = E + (size_t)(b * 32 + r) * 64 + cg;
    const float* Pb = P + (size_t)(b * 32 + r) * 8;
    for (int h = 0; h < ch; ++h) {
      float p = Pb[h]; float4 e = Eb[h * 8];
      Sin.x = p * Sin.x + e.x; Sin.y = p * Sin.y + e.y;
      Sin.z = p * Sin.z + e.z; Sin.w = p * Sin.w + e.w;
    }
    for (int h = 0; h < sub; ++h) {
      float p = sP[h]; float4 e = sE[h * 8 + cg];
      Sin.x = p * Sin.x + e.x; Sin.y = p * Sin.y + e.y;
      Sin.z = p * Sin.z + e.z; Sin.w = p * Sin.w + e.w;
    }
    float4 bb = ((const float4*)bb2)[r * 8 + cg];
    const float4* x4 = (const float4*)x;
    float4* out4 = (float4*)out;
    #pragma unroll
    for (int i = 0; i < 4; ++i) {
      float d = dec[sub * 4 + i];
      Sin.x = d * Sin.x + xv[i].x; Sin.y = d * Sin.y + xv[i].y;
      Sin.z = d * Sin.z + xv[i].z; Sin.w = d * Sin.w + xv[i].w;
      float4 rx = x4[base + (size_t)i * 256];
      float4 oi;
      oi.x = Sin.x + rx.x + bb.x; oi.y = Sin.y + rx.y + bb.y;
      oi.z = Sin.z + rx.z + bb.z; oi.w = Sin.w + rx.w + bb.w;
      out4[base + (size_t)i * 256] = oi;
    }
  }
}

// ---- LN2: 16 tokens/block; reads out, subtracts bb2 -> fn (fp8, MX pack NK=8).
__global__ __launch_bounds__(256) void k_ln2(
    const float* __restrict__ out, const float* __restrict__ bb2,
    const float* __restrict__ g, const float* __restrict__ bta,
    unsigned char* __restrict__ fn) {
  __shared__ __align__(16) unsigned char sC[16384];
  int tid = threadIdx.x;
  int t15 = tid >> 4;                 // token within block
  int kc = tid & 15;
  int tok = (blockIdx.x << 4) + t15;
  const float4* row = (const float4*)(out + (size_t)tok * 1024);
  const float4* b4 = (const float4*)bb2;
  float4 v[16];
  float s = 0.f, ss = 0.f;
  #pragma unroll
  for (int ci = 0; ci < 4; ++ci) {
    int cc = kc + ci * 16;
    #pragma unroll
    for (int q = 0; q < 4; ++q) {
      float4 xv = row[cc * 4 + q];
      float4 bb = b4[cc * 4 + q];
      xv.x -= bb.x; xv.y -= bb.y; xv.z -= bb.z; xv.w -= bb.w;
      v[ci * 4 + q] = xv;
      s += xv.x + xv.y + xv.z + xv.w;
      ss += xv.x * xv.x + xv.y * xv.y + xv.z * xv.z + xv.w * xv.w;
    }
  }
  #pragma unroll
  for (int o = 1; o < 16; o <<= 1) { s += __shfl_xor(s, o); ss += __shfl_xor(ss, o); }
  float m = s * (1.0f / 1024.0f);
  float var = ss * (1.0f / 1024.0f) - m * m;
  float inv = rsqrtf(var + EPSF);
  #pragma unroll
  for (int ci = 0; ci < 4; ++ci) {
    int cc = kc + ci * 16;
    int pk[4];
    #pragma unroll
    for (int q = 0; q < 4; ++q) {
      float4 gv = ((const float4*)g)[cc * 4 + q];
      float4 bv = ((const float4*)bta)[cc * 4 + q];
      float4 xv = v[ci * 4 + q];
      float f0 = (xv.x - m) * inv * gv.x + bv.x;
      float f1 = (xv.y - m) * inv * gv.y + bv.y;
      float f2 = (xv.z - m) * inv * gv.z + bv.z;
      float f3 = (xv.w - m) * inv * gv.w + bv.w;
      int p = __builtin_amdgcn_cvt_pk_fp8_f32(f0, f1, 0, false);
      pk[q] = __builtin_amdgcn_cvt_pk_fp8_f32(f2, f3, p, true);
    }
    int loc = (cc >> 3) * 2048 + (cc & 1) * 1024 + (((cc >> 1) & 3) * 16 + t15) * 16;
    loc ^= ((loc >> 8) & 7) << 4;     // bank swizzle (involution)
    int4 o4; o4.x = pk[0]; o4.y = pk[1]; o4.z = pk[2]; o4.w = pk[3];
    *(int4*)(sC + loc) = o4;
  }
  __syncthreads();
  unsigned char* dst = fn + (size_t)blockIdx.x * 16384;
  #pragma unroll
  for (int p = 0; p < 4; ++p) {
    int a = (p * 256 + tid) * 16;
    int sa = a ^ (((a >> 8) & 7) << 4);
    *(int4*)(dst + a) = *(const int4*)(sC + sa);
  }
}

// ---- GEMM1: 128x128 tile, K=1024, BK=128, 8 stages, double-buffered LDS with
// counted vmcnt prefetch. Epilogue: fast-gelu(acc/16+bias) -> fp8 -> LDS repack
// -> hbf (MX pack NK=32)
__global__ __launch_bounds__(256, 2) void k_gemm1(
    const unsigned char* __restrict__ Ap, const unsigned char* __restrict__ Bp,
    const float* __restrict__ bias, unsigned char* __restrict__ C8) {
  __shared__ __align__(16) unsigned char sAB[65536];   // 2 x (16K A + 16K B)
  int L = blockIdx.x;
  int xcd = L & 7;
  int nq = xcd & 3, mh = xcd >> 2;
  int rest = L >> 3;
  int nx = rest & 7, my = rest >> 3;
  int n0 = (nq * 8 + nx) * 128;
  int m0 = (mh * 8 + my) * 128;
  int tid = threadIdx.x;
  int wave = tid >> 6, lane = tid & 63;
  int wr = wave >> 1, wc = wave & 1;
  int l15 = lane & 15, quad = lane >> 4;

  f32x4 zero = {0.0f, 0.0f, 0.0f, 0.0f};
  f32x4 acc[4][4];
  #pragma unroll
  for (int i = 0; i < 4; ++i)
    #pragma unroll
    for (int j = 0; j < 4; ++j) acc[i][j] = zero;

  const unsigned char* gsrc = (wave < 2) ? Ap : Bp;
  int rt0 = (wave < 2) ? (m0 >> 4) : (n0 >> 4);
  int aoff = (wave < 2) ? 0 : 16384;
  int w01 = wave & 1;

  #pragma unroll
  for (int t = 0; t < 8; ++t) {
    int idx = w01 * 8 + t, rt = idx >> 1, h = idx & 1;
    async_load16(gsrc + ((size_t)(rt0 + rt) * 8 + 0) * 2048 + h * 1024 + lane * 16,
                 sAB + aoff + rt * 2048 + h * 1024 + lane * 16);
  }

  #pragma unroll 1
  for (int st = 0; st < 8; ++st) {
    int cur = (st & 1) * 32768;
    if (st < 7) {
      int nxt = cur ^ 32768;
      #pragma unroll
      for (int t = 0; t < 8; ++t) {
        int idx = w01 * 8 + t, rt = idx >> 1, h = idx & 1;
        async_load16(gsrc + ((size_t)(rt0 + rt) * 8 + st + 1) * 2048 + h * 1024 + lane * 16,
                     sAB + nxt + aoff + rt * 2048 + h * 1024 + lane * 16);
      }
      asm volatile("s_waitcnt vmcnt(8)" ::: "memory");
    } else {
      asm volatile("s_waitcnt vmcnt(0)" ::: "memory");
    }
    __builtin_amdgcn_s_barrier();
    const unsigned char* sA = sAB + cur;
    const unsigned char* sB = sAB + cur + 16384;
    // cache B fragments; stream A fragments (lower peak VGPR)
    i32x8 bf[4];
    #pragma unroll
    for (int j = 0; j < 4; ++j) {
      const unsigned char* pb = sB + (wc * 4 + j) * 2048 + lane * 16;
      i32x4 lo = *(const i32x4*)pb;
      i32x4 hi = *(const i32x4*)(pb + 1024);
      bf[j] = __builtin_shufflevector(lo, hi, 0, 1, 2, 3, 4, 5, 6, 7);
    }
    #pragma unroll
    for (int i = 0; i < 4; ++i) {
      const unsigned char* pa = sA + (wr * 4 + i) * 2048 + lane * 16;
      i32x4 lo = *(const i32x4*)pa;
      i32x4 hi = *(const i32x4*)(pa + 1024);
      i32x8 a = __builtin_shufflevector(lo, hi, 0, 1, 2, 3, 4, 5, 6, 7);
      #pragma unroll
      for (int j = 0; j < 4; ++j)
        acc[i][j] = __builtin_amdgcn_mfma_scale_f32_16x16x128_f8f6f4(
            a, bf[j], acc[i][j], 0, 0, 0, 0x7F7F7F7F, 0, 0x7F7F7F7F);
    }
    asm volatile("s_waitcnt lgkmcnt(0)" ::: "memory");
    __builtin_amdgcn_s_barrier();
  }

  // epilogue: fast gelu (sigmoid-form tanh approx; err ~3e-3 << fp8 step)
  unsigned char* sC = sAB;
  #pragma unroll
  for (int i = 0; i < 4; ++i) {
    #pragma unroll
    for (int j = 0; j < 4; ++j) {
      int col_l = wc * 64 + j * 16 + l15;    // k_l of GEMM2, 0..127
      float bval = bias[n0 + col_l];
      int half2 = (col_l >> 4) & 1, lb = (col_l >> 5) & 3;
      unsigned char* ld = sC + (wr * 4 + i) * 2048 + half2 * 1024 +
                          (lb * 16 + quad * 4) * 16 + l15;
      float vv[4];
      #pragma unroll
      for (int v = 0; v < 4; ++v) {
        float val = acc[i][j][v] * 0.0625f + bval;
        float u = val * (0.7978845608f + 0.035677408f * val * val);
        vv[v] = val / (1.0f + __expf(-2.0f * u));
      }
      int p01 = __builtin_amdgcn_cvt_pk_fp8_f32(vv[0], vv[1], 0, false);
      int p23 = __builtin_amdgcn_cvt_pk_fp8_f32(vv[2], vv[3], 0, false);
      ld[0 * 16] = (unsigned char)(p01 & 0xff);
      ld[1 * 16] = (unsigned char)((p01 >> 8) & 0xff);
      ld[2 * 16] = (unsigned char)(p23 & 0xff);
      ld[3 * 16] = (unsigned char)((p23 >> 8) & 0xff);
    }
  }
  __syncthreads();
  int mt2_0 = m0 >> 4, kp2 = n0 >> 7;       // hbf: NK2 = 32
  #pragma unroll
  for (int p = 0; p < 4; ++p) {
    int ci = p * 256 + tid;
    int s = ci >> 7, off = (ci & 127) * 16;
    *(int4*)(C8 + ((size_t)(mt2_0 + s) * 32 + kp2) * 2048 + off) =
        *(const int4*)(sC + s * 2048 + off);
  }
}

// ---- GEMM2: 64x64 tile, full K=4096 (no split-K, no atomics), BK=256,
// 16 stages, 512 blocks (2/CU), double-buffered LDS, counted vmcnt prefetch.
// 2D XCD swizzle: xcd = (m-quarter<<1)|n-half -> 2MB A + 2MB B per XCD (L2-fit).
// Epilogue: plain RMW out += acc/16.
__global__ __launch_bounds__(256, 2) void k_gemm2(
    const unsigned char* __restrict__ Ap, const unsigned char* __restrict__ Bp,
    float* __restrict__ O) {
  __shared__ __align__(16) unsigned char sAB[65536];   // 2 x (16K A + 16K B)
  int L = blockIdx.x;
  int xcd = L & 7;
  int mq = xcd >> 1, nh = xcd & 1;
  int rest = L >> 3;
  int nx = rest & 7, my = rest >> 3;
  int n0 = (nh * 8 + nx) * 64;
  int m0 = (mq * 8 + my) * 64;
  int tid = threadIdx.x;
  int wave = tid >> 6, lane = tid & 63;
  int wr = wave >> 1, wc = wave & 1;
  int l15 = lane & 15, quad = lane >> 4;

  f32x4 zero = {0.0f, 0.0f, 0.0f, 0.0f};
  f32x4 acc[2][2];
  #pragma unroll
  for (int i = 0; i < 2; ++i)
    #pragma unroll
    for (int j = 0; j < 2; ++j) acc[i][j] = zero;

  // staging: waves 0-1 stage A (8 sb = 4 rt x 2 kt), waves 2-3 stage B
  const unsigned char* gsrc = (wave < 2) ? Ap : Bp;
  int rt0 = (wave < 2) ? (m0 >> 4) : (n0 >> 4);
  int aoff = (wave < 2) ? 0 : 16384;
  int w01 = wave & 1;

  #pragma unroll
  for (int t = 0; t < 8; ++t) {
    int idx = w01 * 8 + t, sb = idx >> 1, h = idx & 1;
    int rt = sb >> 1, kt = sb & 1;
    async_load16(gsrc + ((size_t)(rt0 + rt) * 32 + kt) * 2048 + h * 1024 + lane * 16,
                 sAB + aoff + sb * 2048 + h * 1024 + lane * 16);
  }

  #pragma unroll 1
  for (int st = 0; st < 16; ++st) {
    int cur = (st & 1) * 32768;
    if (st < 15) {
      int nxt = cur ^ 32768;
      #pragma unroll
      for (int t = 0; t < 8; ++t) {
        int idx = w01 * 8 + t, sb = idx >> 1, h = idx & 1;
        int rt = sb >> 1, kt = sb & 1;
        async_load16(
            gsrc + ((size_t)(rt0 + rt) * 32 + (st + 1) * 2 + kt) * 2048 + h * 1024 + lane * 16,
            sAB + nxt + aoff + sb * 2048 + h * 1024 + lane * 16);
      }
      asm volatile("s_waitcnt vmcnt(8)" ::: "memory");
    } else {
      asm volatile("s_waitcnt vmcnt(0)" ::: "memory");
    }
    __builtin_amdgcn_s_barrier();
    const unsigned char* sA = sAB + cur;
    const unsigned char* sB = sAB + cur + 16384;
    #pragma unroll
    for (int kl = 0; kl < 2; ++kl) {
      i32x8 af[2], bf[2];
      #pragma unroll
      for (int i = 0; i < 2; ++i) {
        const unsigned char* pa = sA + ((wr * 2 + i) * 2 + kl) * 2048 + lane * 16;
        i32x4 lo = *(const i32x4*)pa;
        i32x4 hi = *(const i32x4*)(pa + 1024);
        af[i] = __builtin_shufflevector(lo, hi, 0, 1, 2, 3, 4, 5, 6, 7);
      }
      #pragma unroll
      for (int j = 0; j < 2; ++j) {
        const unsigned char* pb = sB + ((wc * 2 + j) * 2 + kl) * 2048 + lane * 16;
        i32x4 lo = *(const i32x4*)pb;
        i32x4 hi = *(const i32x4*)(pb + 1024);
        bf[j] = __builtin_shufflevector(lo, hi, 0, 1, 2, 3, 4, 5, 6, 7);
      }
      #pragma unroll
      for (int i = 0; i < 2; ++i)
        #pragma unroll
        for (int j = 0; j < 2; ++j)
          acc[i][j] = __builtin_amdgcn_mfma_scale_f32_16x16x128_f8f6f4(
              af[i], bf[j], acc[i][j], 0, 0, 0, 0x7F7F7F7F, 0, 0x7F7F7F7F);
    }
    asm volatile("s_waitcnt lgkmcnt(0)" ::: "memory");
    __builtin_amdgcn_s_barrier();
  }

  // epilogue: plain read-modify-write (unique block per output tile)
  #pragma unroll
  for (int i = 0; i < 2; ++i)
    #pragma unroll
    for (int j = 0; j < 2; ++j) {
      int col = n0 + wc * 32 + j * 16 + l15;
      #pragma unroll
      for (int v = 0; v < 4; ++v) {
        int row = m0 + wr * 32 + i * 16 + quad * 4 + v;
        float* p = &O[(size_t)row * 1024 + col];
        *p = *p + acc[i][j][v] * 0.0625f;
      }
    }
}

extern "C" void kernel_launch(void* const* d_in, const int* in_sizes, int n_in,
                              void* d_out, int out_size, void* d_ws, size_t ws_size,
                              hipStream_t stream) {
  const float* x     = (const float*)d_in[0];
  const float* log_A = (const float*)d_in[1];
  const float* w_dt  = (const float*)d_in[2];
  const float* b_dt  = (const float*)d_in[3];
  const float* g_ssm = (const float*)d_in[4];
  const float* b_ssm = (const float*)d_in[5];
  const float* g_ffn = (const float*)d_in[6];
  const float* b_ffn = (const float*)d_in[7];
  const float* W1    = (const float*)d_in[8];
  const float* bb1   = (const float*)d_in[9];
  const float* W2    = (const float*)d_in[10];
  const float* bb2   = (const float*)d_in[11];
  float* out = (float*)d_out;

  const size_t MB = 1u << 20;
  char* ws = (char*)d_ws;
  unsigned short* xn   = (unsigned short*)(ws);              // 0-4 bf16
  unsigned char* W1t   = (unsigned char*)(ws + 4 * MB);      // 4-8 fp8 MX-pack
  float* loga          = (float*)(ws + 8 * MB);              // 256 KB
  float4* Ebuf         = (float4*)(ws + 8 * MB + 262144);    // 64 KB
  float* Pbuf          = (float*)(ws + 8 * MB + 393216);     // 2 KB
  unsigned char* fn    = (unsigned char*)(ws + 9 * MB);      // 9-11 fp8 MX-pack
  unsigned char* W2t   = (unsigned char*)(ws + 11 * MB);     // 11-15 fp8 MX-pack
  unsigned char* hbf   = (unsigned char*)(ws + 15 * MB);     // 15-23 fp8 MX-pack

  k_ln1<<<2048, 256, 0, stream>>>(x, g_ssm, b_ssm, w_dt, b_dt, log_A, xn, loga);
  // scan pass 0 (512) + W1 pack (1024) co-scheduled
  k_scan_pack<0, 8><<<1536, 256, 0, stream>>>(xn, x, loga, Ebuf, Pbuf, bb2, out,
                                              W1, W1t, 4096);
  // scan pass 1 (512) + W2 pack (1024) co-scheduled
  k_scan_pack<1, 32><<<1536, 256, 0, stream>>>(xn, x, loga, Ebuf, Pbuf, bb2, out,
                                               W2, W2t, 1024);
  k_ln2<<<128, 256, 0, stream>>>(out, bb2, g_ffn, b_ffn, fn);
  // GEMM1: M=2048, N=4096, K=1024 (NK=8), 512 blocks
  k_gemm1<<<512, 256, 0, stream>>>(fn, W1t, bb1, hbf);
  // GEMM2: M=2048, N=1024, K=4096 (NK=32), 512 blocks, full-K, no atomics
  k_gemm2<<<512, 256, 0, stream>>>(hbf, W2t, out);
}